// Round 1
// baseline (326.214 us; speedup 1.0000x reference)
//
#include <hip/hip_runtime.h>
#include <stdint.h>

// Problem constants: B=2, S=2048, D=768, H=12, hd=64
typedef float v4f __attribute__((ext_vector_type(4)));
typedef short v8s __attribute__((ext_vector_type(8)));

#define AS1 __attribute__((address_space(1)))
#define AS3 __attribute__((address_space(3)))

__device__ __forceinline__ void load16_to_lds(const void* g, void* l) {
  __builtin_amdgcn_global_load_lds((AS1 void*)g, (AS3 void*)l, 16, 0, 0);
}

__device__ __forceinline__ unsigned short f2bf(float f) {
  union { float f; uint32_t u; } v; v.f = f;
  uint32_t u = v.u;
  return (unsigned short)((u + 0x7FFFu + ((u >> 16) & 1u)) >> 16);
}

// ---------------------------------------------------------------------------
// Kernel 1: pack mask (bool or int32, runtime-detected) into 1 bit per entry.
// bits[(b*2048+q)*64 + kk/32] bit (kk&31) == 1  -> masked (-inf)
// grid: 1024 x 256 ; 262144 output words
// ---------------------------------------------------------------------------
__global__ __launch_bounds__(256) void pack_mask_kernel(
    const uint32_t* __restrict__ mask, uint32_t* __restrict__ bits) {
  __shared__ int s_i32;
  const int tid = threadIdx.x;
  if (tid == 0) s_i32 = 1;
  __syncthreads();
  // int32 mode iff first 256 words are all <= 1 (bool-byte mode fails this
  // with probability 8^-256 since random bytes land in positions 1..3)
  if (mask[tid] > 1u) s_i32 = 0;
  __syncthreads();
  const int i32mode = s_i32;
  const int wi = blockIdx.x * 256 + tid;
  uint32_t w = 0;
  if (i32mode) {
    const uint32_t* p = mask + (size_t)wi * 32;
#pragma unroll
    for (int j = 0; j < 32; ++j) w |= (p[j] ? 1u : 0u) << j;
  } else {
    const uint32_t* p = mask + (size_t)wi * 8;
#pragma unroll
    for (int j8 = 0; j8 < 8; ++j8) {
      uint32_t u = p[j8];
#pragma unroll
      for (int k = 0; k < 4; ++k)
        w |= (((u >> (8 * k)) & 0xFFu) ? 1u : 0u) << (j8 * 4 + k);
    }
  }
  bits[wi] = w;
}

// ---------------------------------------------------------------------------
// Kernel 2: QKV projection GEMM.  C = A(4096x768) @ W^T(768x768) + bias.
// 128x128 tile, BK=32, 4 waves (2x2), each wave 4x4 MFMA 16x16x32 bf16.
// fp32 inputs converted to bf16 during LDS staging.
// z=0: Q -> Qb[(b*2048+s)*768+n]  z=1: K -> Kb same layout
// z=2: V -> Vt[(b*768+n)*2048 + s]  (transposed for PV B-operand reads)
// ---------------------------------------------------------------------------
__global__ __launch_bounds__(256) void gemm_qkv_kernel(
    const float* __restrict__ q_in, const float* __restrict__ k_in,
    const float* __restrict__ v_in,
    const float* __restrict__ wq, const float* __restrict__ bq,
    const float* __restrict__ wk, const float* __restrict__ bk,
    const float* __restrict__ wv, const float* __restrict__ bv,
    unsigned short* __restrict__ Qb, unsigned short* __restrict__ Kb,
    unsigned short* __restrict__ Vt) {
  const int which = blockIdx.z;
  const float* A;
  const float* W;
  const float* bias;
  if (which == 0)      { A = q_in; W = wq; bias = bq; }
  else if (which == 1) { A = k_in; W = wk; bias = bk; }
  else                 { A = v_in; W = wv; bias = bv; }

  const int m0 = blockIdx.x * 128;
  const int n0 = blockIdx.y * 128;
  const int tid = threadIdx.x;
  const int lane = tid & 63;
  const int wid = tid >> 6;        // wave 0..3
  const int wm = wid >> 1, wn = wid & 1;
  const int l16 = lane & 15, quad = lane >> 4;

  __shared__ __align__(16) unsigned short As[128 * 32];
  __shared__ __align__(16) unsigned short Bs[128 * 32];

  v4f acc[4][4];
#pragma unroll
  for (int i = 0; i < 4; ++i)
#pragma unroll
    for (int j = 0; j < 4; ++j) { v4f z = {0.f, 0.f, 0.f, 0.f}; acc[i][j] = z; }

  for (int k0 = 0; k0 < 768; k0 += 32) {
    // stage A tile (128x32 fp32 -> bf16). 1024 float4-chunks, 4 per thread.
#pragma unroll
    for (int i = 0; i < 4; ++i) {
      int c = tid + i * 256;
      int row = c >> 3, col4 = (c & 7) * 4;
      const float4 f = *(const float4*)&A[(size_t)(m0 + row) * 768 + k0 + col4];
      ushort4 h;
      h.x = f2bf(f.x); h.y = f2bf(f.y); h.z = f2bf(f.z); h.w = f2bf(f.w);
      *(ushort4*)&As[row * 32 + col4] = h;
    }
    // stage B tile: rows of W (n index), cols k
#pragma unroll
    for (int i = 0; i < 4; ++i) {
      int c = tid + i * 256;
      int row = c >> 3, col4 = (c & 7) * 4;
      const float4 f = *(const float4*)&W[(size_t)(n0 + row) * 768 + k0 + col4];
      ushort4 h;
      h.x = f2bf(f.x); h.y = f2bf(f.y); h.z = f2bf(f.z); h.w = f2bf(f.w);
      *(ushort4*)&Bs[row * 32 + col4] = h;
    }
    __syncthreads();

    v8s af[4], bf[4];
#pragma unroll
    for (int i = 0; i < 4; ++i)
      af[i] = *(const v8s*)&As[(wm * 64 + i * 16 + l16) * 32 + quad * 8];
#pragma unroll
    for (int j = 0; j < 4; ++j)
      bf[j] = *(const v8s*)&Bs[(wn * 64 + j * 16 + l16) * 32 + quad * 8];
#pragma unroll
    for (int i = 0; i < 4; ++i)
#pragma unroll
      for (int j = 0; j < 4; ++j)
        acc[i][j] = __builtin_amdgcn_mfma_f32_16x16x32_bf16(af[i], bf[j],
                                                            acc[i][j], 0, 0, 0);
    __syncthreads();
  }

  // epilogue: D[row=quad*4+r][col=l16] per 16x16 tile
#pragma unroll
  for (int i = 0; i < 4; ++i) {
#pragma unroll
    for (int j = 0; j < 4; ++j) {
      const int mbase = m0 + wm * 64 + i * 16 + quad * 4;
      const int n = n0 + wn * 64 + j * 16 + l16;
      const float bv_ = bias[n];
#pragma unroll
      for (int r = 0; r < 4; ++r) {
        const int m = mbase + r;
        const unsigned short hb = f2bf(acc[i][j][r] + bv_);
        if (which == 0)      Qb[(size_t)m * 768 + n] = hb;
        else if (which == 1) Kb[(size_t)m * 768 + n] = hb;
        else {
          const int bb = m >> 11, ss = m & 2047;
          Vt[((size_t)bb * 768 + n) * 2048 + ss] = hb;
        }
      }
    }
  }
}

// ---------------------------------------------------------------------------
// Kernel 3: flash attention.  grid (32 q-tiles, 12 heads, 2 batches), 256 thr.
// Wave w owns q rows q0+w*16..+15.  K-tiles of 64 keys; online softmax.
// Output written bf16 in the reference's scrambled concat order.
// ---------------------------------------------------------------------------
__global__ __launch_bounds__(256) void attn_kernel(
    const unsigned short* __restrict__ Qb, const unsigned short* __restrict__ Kb,
    const unsigned short* __restrict__ Vt, const uint32_t* __restrict__ mbits,
    unsigned short* __restrict__ X) {
  const int q0 = blockIdx.x * 64;
  const int h = blockIdx.y;
  const int b = blockIdx.z;
  const int tid = threadIdx.x;
  const int w = tid >> 6;
  const int lane = tid & 63;
  const int l16 = lane & 15, quad = lane >> 4;

  __shared__ __align__(16) unsigned short Kl[64 * 64];   // [key][dim]
  __shared__ __align__(16) unsigned short Vl[64 * 64];   // [dim][key]
  __shared__ __align__(16) unsigned short Pl[4][16 * 64];

  // Q fragments (A-operand), once per block
  v8s aq[2];
  {
    const unsigned short* qp =
        Qb + (size_t)(b * 2048 + q0 + w * 16 + l16) * 768 + h * 64 + quad * 8;
    aq[0] = *(const v8s*)qp;
    aq[1] = *(const v8s*)(qp + 32);
  }

  float mrun[4], lrun[4];
  v4f o[4];
#pragma unroll
  for (int r = 0; r < 4; ++r) { mrun[r] = -1e30f; lrun[r] = 0.f; }
#pragma unroll
  for (int nt = 0; nt < 4; ++nt) { v4f z = {0.f, 0.f, 0.f, 0.f}; o[nt] = z; }

  const float inv_scaler = 0.03608439182435161f;  // 1/sqrt(768)

  for (int kk0 = 0; kk0 < 2048; kk0 += 64) {
    // stage K tile (64 keys x 64 dims) and V^T tile (64 dims x 64 keys)
    {
      const int rbase = w * 16;
      const unsigned short* kg =
          Kb + (size_t)(b * 2048 + kk0 + rbase) * 768 + h * 64;
      const unsigned short* vg =
          Vt + (size_t)(b * 768 + h * 64 + rbase) * 2048 + kk0;
      const int rsub = lane >> 3;      // 0..7
      const int csub = (lane & 7) * 8; // element offset of 16B chunk
#pragma unroll
      for (int iss = 0; iss < 2; ++iss) {
        load16_to_lds(kg + (size_t)(iss * 8 + rsub) * 768 + csub,
                      &Kl[(rbase + iss * 8) * 64]);
        load16_to_lds(vg + (size_t)(iss * 8 + rsub) * 2048 + csub,
                      &Vl[(rbase + iss * 8) * 64]);
      }
    }
    __syncthreads();

    // S = Q @ K^T  (per wave: 16 x 64)
    v4f sacc[4];
#pragma unroll
    for (int nt = 0; nt < 4; ++nt) { v4f z = {0.f, 0.f, 0.f, 0.f}; sacc[nt] = z; }
#pragma unroll
    for (int kt = 0; kt < 2; ++kt) {
      v8s bk[4];
#pragma unroll
      for (int nt = 0; nt < 4; ++nt)
        bk[nt] = *(const v8s*)&Kl[(nt * 16 + l16) * 64 + kt * 32 + quad * 8];
#pragma unroll
      for (int nt = 0; nt < 4; ++nt)
        sacc[nt] = __builtin_amdgcn_mfma_f32_16x16x32_bf16(aq[kt], bk[nt],
                                                           sacc[nt], 0, 0, 0);
    }

    // mask + online softmax (rows quad*4+r, cols nt*16+l16)
    const uint32_t* mrow =
        mbits + (size_t)(b * 2048 + q0 + w * 16 + quad * 4) * 64 + (kk0 >> 5);
    float p[4][4], alpha[4];
#pragma unroll
    for (int r = 0; r < 4; ++r) {
      const uint32_t w0 = mrow[r * 64];
      const uint32_t w1 = mrow[r * 64 + 1];
      float sv[4];
      float mx = -1e30f;
#pragma unroll
      for (int nt = 0; nt < 4; ++nt) {
        const int cidx = nt * 16 + l16;
        const uint32_t wsel = (cidx & 32) ? w1 : w0;
        float s = sacc[nt][r] * inv_scaler;
        if ((wsel >> (cidx & 31)) & 1u) s = -1e30f;
        sv[nt] = s;
        mx = fmaxf(mx, s);
      }
#pragma unroll
      for (int off = 1; off < 16; off <<= 1) mx = fmaxf(mx, __shfl_xor(mx, off, 64));
      const float mnew = fmaxf(mrun[r], mx);
      alpha[r] = __expf(mrun[r] - mnew);
      float rs = 0.f;
#pragma unroll
      for (int nt = 0; nt < 4; ++nt) {
        const float pv = __expf(sv[nt] - mnew);
        p[nt][r] = pv;
        rs += pv;
      }
#pragma unroll
      for (int off = 1; off < 16; off <<= 1) rs += __shfl_xor(rs, off, 64);
      lrun[r] = lrun[r] * alpha[r] + rs;
      mrun[r] = mnew;
    }

    // rescale O, write P (C-layout -> LDS -> A-layout)
#pragma unroll
    for (int nt = 0; nt < 4; ++nt)
#pragma unroll
      for (int r = 0; r < 4; ++r) o[nt][r] *= alpha[r];
#pragma unroll
    for (int nt = 0; nt < 4; ++nt)
#pragma unroll
      for (int r = 0; r < 4; ++r)
        Pl[w][(quad * 4 + r) * 64 + nt * 16 + l16] = f2bf(p[nt][r]);

    // O += P @ V
#pragma unroll
    for (int kt = 0; kt < 2; ++kt) {
      const v8s ap = *(const v8s*)&Pl[w][l16 * 64 + kt * 32 + quad * 8];
#pragma unroll
      for (int nt = 0; nt < 4; ++nt) {
        const v8s bv = *(const v8s*)&Vl[(nt * 16 + l16) * 64 + kt * 32 + quad * 8];
        o[nt] = __builtin_amdgcn_mfma_f32_16x16x32_bf16(ap, bv, o[nt], 0, 0, 0);
      }
    }
    __syncthreads();
  }

  // epilogue: faithful reshape scramble.  2h+b = 12*b2 + h2
  const int hb2 = 2 * h + b;
  const int b2 = (hb2 >= 12) ? 1 : 0;
  const int h2 = hb2 - 12 * b2;
#pragma unroll
  for (int r = 0; r < 4; ++r) {
    const int q = q0 + w * 16 + quad * 4 + r;
    const float inv_l = 1.f / lrun[r];
#pragma unroll
    for (int nt = 0; nt < 4; ++nt) {
      const int d = nt * 16 + l16;
      const size_t f = (size_t)h2 * 262144 + (size_t)q * 128 + b2 * 64 + d;
      X[f] = f2bf(o[nt][r] * inv_l);
    }
  }
}

// ---------------------------------------------------------------------------
// Kernel 4: out = X(4096x768 bf16) @ Wc^T + bc + query  (fp32 out)
// A staged via global_load_lds (bf16 source); B converted fp32->bf16.
// ---------------------------------------------------------------------------
__global__ __launch_bounds__(256) void gemm2_kernel(
    const unsigned short* __restrict__ X, const float* __restrict__ Wc,
    const float* __restrict__ bc, const float* __restrict__ query,
    float* __restrict__ out) {
  const int m0 = blockIdx.x * 128;
  const int n0 = blockIdx.y * 128;
  const int tid = threadIdx.x;
  const int lane = tid & 63;
  const int wid = tid >> 6;
  const int wm = wid >> 1, wn = wid & 1;
  const int l16 = lane & 15, quad = lane >> 4;

  __shared__ __align__(16) unsigned short As[128 * 32];
  __shared__ __align__(16) unsigned short Bs[128 * 32];

  v4f acc[4][4];
#pragma unroll
  for (int i = 0; i < 4; ++i)
#pragma unroll
    for (int j = 0; j < 4; ++j) { v4f z = {0.f, 0.f, 0.f, 0.f}; acc[i][j] = z; }

  for (int k0 = 0; k0 < 768; k0 += 32) {
    // A: 512 16B-chunks; wave w covers chunks [w*128, w*128+128)
    {
      const int cbase = wid * 128;
#pragma unroll
      for (int iss = 0; iss < 2; ++iss) {
        const int c = cbase + iss * 64 + lane;
        const int row = c >> 2, col8 = (c & 3) * 8;
        load16_to_lds(X + (size_t)(m0 + row) * 768 + k0 + col8,
                      &As[(cbase + iss * 64) * 8]);
      }
    }
    // B: Wc fp32 -> bf16
#pragma unroll
    for (int i = 0; i < 4; ++i) {
      int c = tid + i * 256;
      int row = c >> 3, col4 = (c & 7) * 4;
      const float4 f = *(const float4*)&Wc[(size_t)(n0 + row) * 768 + k0 + col4];
      ushort4 h;
      h.x = f2bf(f.x); h.y = f2bf(f.y); h.z = f2bf(f.z); h.w = f2bf(f.w);
      *(ushort4*)&Bs[row * 32 + col4] = h;
    }
    __syncthreads();

    v8s af[4], bf[4];
#pragma unroll
    for (int i = 0; i < 4; ++i)
      af[i] = *(const v8s*)&As[(wm * 64 + i * 16 + l16) * 32 + quad * 8];
#pragma unroll
    for (int j = 0; j < 4; ++j)
      bf[j] = *(const v8s*)&Bs[(wn * 64 + j * 16 + l16) * 32 + quad * 8];
#pragma unroll
    for (int i = 0; i < 4; ++i)
#pragma unroll
      for (int j = 0; j < 4; ++j)
        acc[i][j] = __builtin_amdgcn_mfma_f32_16x16x32_bf16(af[i], bf[j],
                                                            acc[i][j], 0, 0, 0);
    __syncthreads();
  }

#pragma unroll
  for (int i = 0; i < 4; ++i) {
#pragma unroll
    for (int j = 0; j < 4; ++j) {
      const int mbase = m0 + wm * 64 + i * 16 + quad * 4;
      const int n = n0 + wn * 64 + j * 16 + l16;
      const float bv_ = bc[n];
#pragma unroll
      for (int r = 0; r < 4; ++r) {
        const int m = mbase + r;
        out[(size_t)m * 768 + n] =
            acc[i][j][r] + bv_ + query[(size_t)m * 768 + n];
      }
    }
  }
}

// ---------------------------------------------------------------------------
// Kernel 5: LayerNorm in place on d_out.  One block per row (768 elems).
// ---------------------------------------------------------------------------
__global__ __launch_bounds__(256) void ln_kernel(float* __restrict__ out,
                                                 const float* __restrict__ g,
                                                 const float* __restrict__ bta) {
  const int row = blockIdx.x;
  const int tid = threadIdx.x;
  float x[3];
  float s = 0.f, sq = 0.f;
#pragma unroll
  for (int k = 0; k < 3; ++k) {
    x[k] = out[(size_t)row * 768 + tid + k * 256];
    s += x[k];
    sq += x[k] * x[k];
  }
#pragma unroll
  for (int off = 1; off < 64; off <<= 1) {
    s += __shfl_xor(s, off, 64);
    sq += __shfl_xor(sq, off, 64);
  }
  __shared__ float ss[4], ssq[4];
  const int w = tid >> 6, lane = tid & 63;
  if (lane == 0) { ss[w] = s; ssq[w] = sq; }
  __syncthreads();
  s = ss[0] + ss[1] + ss[2] + ss[3];
  sq = ssq[0] + ssq[1] + ssq[2] + ssq[3];
  const float mu = s * (1.f / 768.f);
  const float var = sq * (1.f / 768.f) - mu * mu;
  const float rstd = rsqrtf(var + 1e-5f);
#pragma unroll
  for (int k = 0; k < 3; ++k) {
    const int cc = tid + k * 256;
    out[(size_t)row * 768 + cc] = g[cc] * (x[k] - mu) * rstd + bta[cc];
  }
}

// ---------------------------------------------------------------------------
extern "C" void kernel_launch(void* const* d_in, const int* in_sizes, int n_in,
                              void* d_out, int out_size, void* d_ws,
                              size_t ws_size, hipStream_t stream) {
  const float* key   = (const float*)d_in[0];
  const float* query = (const float*)d_in[1];
  const float* value = (const float*)d_in[2];
  const uint32_t* mask = (const uint32_t*)d_in[3];
  const float* Wk = (const float*)d_in[4];
  const float* bk = (const float*)d_in[5];
  const float* Wq = (const float*)d_in[6];
  const float* bq = (const float*)d_in[7];
  const float* Wv = (const float*)d_in[8];
  const float* bv = (const float*)d_in[9];
  const float* Wc = (const float*)d_in[10];
  const float* bc = (const float*)d_in[11];
  const float* lng = (const float*)d_in[12];
  const float* lnb = (const float*)d_in[13];

  char* ws = (char*)d_ws;
  uint32_t*       mbits = (uint32_t*)(ws);                 // 1 MB
  unsigned short* Qb = (unsigned short*)(ws + 2097152);    // 6 MB
  unsigned short* Kb = (unsigned short*)(ws + 8388608);    // 6 MB
  unsigned short* Vt = (unsigned short*)(ws + 14680064);   // 6 MB
  unsigned short* X  = (unsigned short*)(ws + 20971520);   // 6 MB  (end ~26 MB)
  float* out = (float*)d_out;

  pack_mask_kernel<<<dim3(1024), dim3(256), 0, stream>>>(mask, mbits);
  gemm_qkv_kernel<<<dim3(32, 6, 3), dim3(256), 0, stream>>>(
      query, key, value, Wq, bq, Wk, bk, Wv, bv, Qb, Kb, Vt);
  attn_kernel<<<dim3(32, 12, 2), dim3(256), 0, stream>>>(Qb, Kb, Vt, mbits, X);
  gemm2_kernel<<<dim3(32, 6), dim3(256), 0, stream>>>(X, Wc, bc, query, out);
  ln_kernel<<<dim3(4096), dim3(256), 0, stream>>>(out, lng, lnb);
}

// Round 2
// 249.530 us; speedup vs baseline: 1.3073x; 1.3073x over previous
//
#include <hip/hip_runtime.h>
#include <stdint.h>

// B=2, S=2048, D=768, H=12, hd=64
typedef float v4f __attribute__((ext_vector_type(4)));
typedef short v8s __attribute__((ext_vector_type(8)));

#define AS1 __attribute__((address_space(1)))
#define AS3 __attribute__((address_space(3)))

__device__ __forceinline__ void load16_to_lds(const void* g, void* l) {
  __builtin_amdgcn_global_load_lds((AS1 void*)g, (AS3 void*)l, 16, 0, 0);
}
__device__ __forceinline__ void load4_to_lds(const void* g, void* l) {
  __builtin_amdgcn_global_load_lds((AS1 void*)g, (AS3 void*)l, 4, 0, 0);
}

__device__ __forceinline__ float fexp2(float x) {
#if __has_builtin(__builtin_amdgcn_exp2f)
  return __builtin_amdgcn_exp2f(x);
#else
  return exp2f(x);
#endif
}

// round-half-up fp32 -> bf16 (1 add + 1 shift)
__device__ __forceinline__ unsigned short f2bf_rn(float f) {
  union { float f; uint32_t u; } v; v.f = f;
  return (unsigned short)((v.u + 0x8000u) >> 16);
}
// pack two fp32 -> bf16x2 dword via v_perm (x in low half)
__device__ __forceinline__ uint32_t pack_bf2(float x, float y) {
  union { float f; uint32_t u; } a, b; a.f = x; b.f = y;
  return __builtin_amdgcn_perm(b.u + 0x8000u, a.u + 0x8000u, 0x07060302u);
}

#define QSCALE 0.052058786f  // log2(e)/sqrt(768), folded into Wq & bq

// ---------------------------------------------------------------------------
// Kernel 1: pack mask into 1 bit/entry. int32 path: coalesced + __ballot.
// ---------------------------------------------------------------------------
__global__ __launch_bounds__(256) void pack_mask_kernel(
    const uint32_t* __restrict__ mask, uint32_t* __restrict__ bits) {
  __shared__ int s_i32;
  const int tid = threadIdx.x;
  if (tid == 0) s_i32 = 1;
  __syncthreads();
  if (mask[tid] > 1u) s_i32 = 0;   // byte-mode detector (P(fail) = 8^-256)
  __syncthreads();
  if (s_i32) {
    const int lane = tid & 63;
    const int gw = (blockIdx.x * 256 + tid) >> 6;  // 0..4095
#pragma unroll 4
    for (int it = 0; it < 32; ++it) {
      const size_t base = (size_t)gw * 2048 + it * 64;
      unsigned long long bal = __ballot(mask[base + lane] != 0u);
      if (lane == 0) *(unsigned long long*)&bits[base >> 5] = bal;
    }
  } else {
    const int wi = blockIdx.x * 256 + tid;
    const uint32_t* p = mask + (size_t)wi * 8;
    uint32_t w = 0;
#pragma unroll
    for (int j8 = 0; j8 < 8; ++j8) {
      uint32_t u = p[j8];
#pragma unroll
      for (int k = 0; k < 4; ++k)
        w |= (((u >> (8 * k)) & 0xFFu) ? 1u : 0u) << (j8 * 4 + k);
    }
    bits[wi] = w;
  }
}

// ---------------------------------------------------------------------------
// Kernel 2: convert 4 weight matrices fp32 -> bf16 (Wq pre-scaled by QSCALE).
// grid (576, 4) x 256; each thread one float4.
// ---------------------------------------------------------------------------
__global__ __launch_bounds__(256) void conv_w_kernel(
    const float* __restrict__ wk, const float* __restrict__ wq,
    const float* __restrict__ wv, const float* __restrict__ wc,
    unsigned short* __restrict__ dk, unsigned short* __restrict__ dq,
    unsigned short* __restrict__ dv, unsigned short* __restrict__ dc) {
  const int y = blockIdx.y;
  const float* s; unsigned short* d; float sc = 1.f;
  if (y == 0)      { s = wk; d = dk; }
  else if (y == 1) { s = wq; d = dq; sc = QSCALE; }
  else if (y == 2) { s = wv; d = dv; }
  else             { s = wc; d = dc; }
  const int i = blockIdx.x * 256 + threadIdx.x;
  float4 f = ((const float4*)s)[i];
  uint2 o;
  o.x = pack_bf2(f.x * sc, f.y * sc);
  o.y = pack_bf2(f.z * sc, f.w * sc);
  ((uint2*)d)[i] = o;
}

// ---------------------------------------------------------------------------
// Kernel 3: QKV GEMM. A fp32 (converted during staging, add+v_perm),
// B bf16 via global_load_lds. 128x128 tile, BK=32, 4 waves 4x4 MFMA.
// z=0: query*Wq(scaled) -> Qb ; z=1: key*Wk -> Kb ; z=2: value*Wv -> Vt(T)
// ---------------------------------------------------------------------------
__global__ __launch_bounds__(256) void gemm_qkv_kernel(
    const float* __restrict__ q_in, const float* __restrict__ k_in,
    const float* __restrict__ v_in,
    const unsigned short* __restrict__ wqb, const unsigned short* __restrict__ wkb,
    const unsigned short* __restrict__ wvb,
    const float* __restrict__ bq, const float* __restrict__ bk,
    const float* __restrict__ bv,
    unsigned short* __restrict__ Qb, unsigned short* __restrict__ Kb,
    unsigned short* __restrict__ Vt) {
  const int which = blockIdx.z;
  const float* A; const unsigned short* Wb; const float* bias; float bscale;
  if (which == 0)      { A = q_in; Wb = wqb; bias = bq; bscale = QSCALE; }
  else if (which == 1) { A = k_in; Wb = wkb; bias = bk; bscale = 1.f; }
  else                 { A = v_in; Wb = wvb; bias = bv; bscale = 1.f; }

  const int m0 = blockIdx.x * 128, n0 = blockIdx.y * 128;
  const int tid = threadIdx.x, lane = tid & 63, wid = tid >> 6;
  const int wm = wid >> 1, wn = wid & 1;
  const int l16 = lane & 15, quad = lane >> 4;

  __shared__ __align__(16) unsigned short As[128 * 32];
  __shared__ __align__(16) unsigned short Bs[128 * 32];

  v4f acc[4][4];
#pragma unroll
  for (int i = 0; i < 4; ++i)
#pragma unroll
    for (int j = 0; j < 4; ++j) { v4f z = {0.f, 0.f, 0.f, 0.f}; acc[i][j] = z; }

  for (int k0 = 0; k0 < 768; k0 += 32) {
    // A: 1024 float4-chunks, 4/thread, fp32->bf16 via add+perm
#pragma unroll
    for (int i = 0; i < 4; ++i) {
      const int c = tid + i * 256;
      const int row = c >> 3, col4 = (c & 7) * 4;
      const float4 f = *(const float4*)&A[(size_t)(m0 + row) * 768 + k0 + col4];
      uint2 o; o.x = pack_bf2(f.x, f.y); o.y = pack_bf2(f.z, f.w);
      *(uint2*)&As[row * 32 + col4] = o;
    }
    // B: 512 16B-chunks via global_load_lds, 2/lane
    {
      const int cbase = wid * 128;
#pragma unroll
      for (int iss = 0; iss < 2; ++iss) {
        const int c = cbase + iss * 64 + lane;
        const int row = c >> 2, col8 = (c & 3) * 8;
        load16_to_lds(Wb + (size_t)(n0 + row) * 768 + k0 + col8,
                      &Bs[(cbase + iss * 64) * 8]);
      }
    }
    __syncthreads();

    v8s af[4], bf[4];
#pragma unroll
    for (int i = 0; i < 4; ++i)
      af[i] = *(const v8s*)&As[(wm * 64 + i * 16 + l16) * 32 + quad * 8];
#pragma unroll
    for (int j = 0; j < 4; ++j)
      bf[j] = *(const v8s*)&Bs[(wn * 64 + j * 16 + l16) * 32 + quad * 8];
#pragma unroll
    for (int i = 0; i < 4; ++i)
#pragma unroll
      for (int j = 0; j < 4; ++j)
        acc[i][j] = __builtin_amdgcn_mfma_f32_16x16x32_bf16(af[i], bf[j],
                                                            acc[i][j], 0, 0, 0);
    __syncthreads();
  }

#pragma unroll
  for (int i = 0; i < 4; ++i) {
#pragma unroll
    for (int j = 0; j < 4; ++j) {
      const int mbase = m0 + wm * 64 + i * 16 + quad * 4;
      const int n = n0 + wn * 64 + j * 16 + l16;
      const float bv_ = bias[n] * bscale;
#pragma unroll
      for (int r = 0; r < 4; ++r) {
        const int m = mbase + r;
        const unsigned short hb = f2bf_rn(acc[i][j][r] + bv_);
        if (which == 0)      Qb[(size_t)m * 768 + n] = hb;
        else if (which == 1) Kb[(size_t)m * 768 + n] = hb;
        else {
          const int bb = m >> 11, ss = m & 2047;
          Vt[((size_t)bb * 768 + n) * 2048 + ss] = hb;
        }
      }
    }
  }
}

// ---------------------------------------------------------------------------
// Kernel 4: attention. No-max exp2 softmax (scores pre-scaled into Wq),
// denominator via ones-column MFMA, XOR-swizzled LDS (conflict-free),
// mask staged to LDS. grid (32,12,2) x 256.
// ---------------------------------------------------------------------------
__global__ __launch_bounds__(256) void attn_kernel(
    const unsigned short* __restrict__ Qb, const unsigned short* __restrict__ Kb,
    const unsigned short* __restrict__ Vt, const uint32_t* __restrict__ mbits,
    unsigned short* __restrict__ X) {
  const int q0 = blockIdx.x * 64;
  const int h = blockIdx.y, b = blockIdx.z;
  const int tid = threadIdx.x, w = tid >> 6, lane = tid & 63;
  const int l16 = lane & 15, quad = lane >> 4, l7 = l16 & 7;

  // rows of Kl/Vl/Pl are 128 B (bank-aliased); 16B-chunk c of row r stored at
  // position c ^ (r&7)  -> all b128 reads/writes spread across all 32 banks.
  __shared__ __align__(16) unsigned short Kl[64 * 64];
  __shared__ __align__(16) unsigned short Vl[64 * 64];
  __shared__ __align__(16) unsigned short Pl[4][16 * 64];
  __shared__ uint32_t Ml[128];

  v8s aq[2];
  {
    const unsigned short* qp =
        Qb + (size_t)(b * 2048 + q0 + w * 16 + l16) * 768 + h * 64 + quad * 8;
    aq[0] = *(const v8s*)qp;
    aq[1] = *(const v8s*)(qp + 32);
  }

  v4f o[4], ol;
#pragma unroll
  for (int nt = 0; nt < 4; ++nt) { v4f z = {0.f, 0.f, 0.f, 0.f}; o[nt] = z; }
  { v4f z = {0.f, 0.f, 0.f, 0.f}; ol = z; }

  // ones-column B fragment: lane l16==0 holds B[0][k]=1.0bf16 for its k-range
  v8s bones;
  {
    const short v1 = (l16 == 0) ? (short)0x3F80 : (short)0;
#pragma unroll
    for (int j = 0; j < 8; ++j) bones[j] = v1;
  }

  const int rsub = lane >> 3;
  const int csub = ((lane & 7) ^ rsub) * 8;  // swizzled global source chunk

  for (int kk0 = 0; kk0 < 2048; kk0 += 64) {
    {
      const unsigned short* kg =
          Kb + (size_t)(b * 2048 + kk0 + w * 16) * 768 + h * 64;
      const unsigned short* vg =
          Vt + (size_t)(b * 768 + h * 64 + w * 16) * 2048 + kk0;
#pragma unroll
      for (int iss = 0; iss < 2; ++iss) {
        load16_to_lds(kg + (size_t)(iss * 8 + rsub) * 768 + csub,
                      &Kl[(w * 16 + iss * 8) * 64]);
        load16_to_lds(vg + (size_t)(iss * 8 + rsub) * 2048 + csub,
                      &Vl[(w * 16 + iss * 8) * 64]);
      }
      if (w < 2) {  // stage 64 rows x 2 mask dwords
        const uint32_t* mg = mbits +
            (size_t)(b * 2048 + q0 + w * 32 + (lane >> 1)) * 64 + (kk0 >> 5) +
            (lane & 1);
        load4_to_lds(mg, &Ml[w * 64]);
      }
    }
    __syncthreads();

    // S = Q K^T (16 x 64 per wave), scores already x log2e/sqrt(768)
    v4f sacc[4];
#pragma unroll
    for (int nt = 0; nt < 4; ++nt) { v4f z = {0.f, 0.f, 0.f, 0.f}; sacc[nt] = z; }
#pragma unroll
    for (int kt = 0; kt < 2; ++kt) {
      v8s bk[4];
#pragma unroll
      for (int nt = 0; nt < 4; ++nt)
        bk[nt] = *(const v8s*)&Kl[(nt * 16 + l16) * 64 +
                                  (((kt * 4 + quad) ^ l7) << 3)];
#pragma unroll
      for (int nt = 0; nt < 4; ++nt)
        sacc[nt] = __builtin_amdgcn_mfma_f32_16x16x32_bf16(aq[kt], bk[nt],
                                                           sacc[nt], 0, 0, 0);
    }

    // P = mask ? 0 : exp2(S); write swizzled (row quad*4+r, col nt*16+l16)
    const int rowb = w * 16 + quad * 4;
    const int hi = l16 >> 3;
#pragma unroll
    for (int r = 0; r < 4; ++r) {
      const uint32_t m0w = Ml[(rowb + r - w * 16 + w * 16) * 2];  // = Ml[(rowb+r)*2]
      const uint32_t m1w = Ml[(rowb + r) * 2 + 1];
      const uint32_t u0 = m0w >> l16, u1 = m1w >> l16;
      const float p0 = (u0 & 1u) ? 0.f : fexp2(sacc[0][r]);
      const float p1 = ((u0 >> 16) & 1u) ? 0.f : fexp2(sacc[1][r]);
      const float p2 = (u1 & 1u) ? 0.f : fexp2(sacc[2][r]);
      const float p3 = ((u1 >> 16) & 1u) ? 0.f : fexp2(sacc[3][r]);
      const int prow = quad * 4 + r, ps = prow & 7;
      const int base = prow * 64 + l7;
      Pl[w][base + (((0 + hi) ^ ps) << 3)] = f2bf_rn(p0);
      Pl[w][base + (((2 + hi) ^ ps) << 3)] = f2bf_rn(p1);
      Pl[w][base + (((4 + hi) ^ ps) << 3)] = f2bf_rn(p2);
      Pl[w][base + (((6 + hi) ^ ps) << 3)] = f2bf_rn(p3);
    }

    // O += P V ; row-sum l += P @ ones (same truncated P -> consistent norm)
#pragma unroll
    for (int kt = 0; kt < 2; ++kt) {
      const v8s ap = *(const v8s*)&Pl[w][l16 * 64 + (((kt * 4 + quad) ^ l7) << 3)];
#pragma unroll
      for (int nt = 0; nt < 4; ++nt) {
        const v8s bv = *(const v8s*)&Vl[(nt * 16 + l16) * 64 +
                                        (((kt * 4 + quad) ^ l7) << 3)];
        o[nt] = __builtin_amdgcn_mfma_f32_16x16x32_bf16(ap, bv, o[nt], 0, 0, 0);
      }
      ol = __builtin_amdgcn_mfma_f32_16x16x32_bf16(ap, bones, ol, 0, 0, 0);
    }
    __syncthreads();
  }

  // epilogue: faithful reshape scramble. 2h+b = 12*b2 + h2
  const int hb2 = 2 * h + b;
  const int b2 = (hb2 >= 12) ? 1 : 0;
  const int h2 = hb2 - 12 * b2;
#pragma unroll
  for (int r = 0; r < 4; ++r) {
    const float lsum = __shfl(ol[r], quad * 16, 64);  // col 0 holds the row sum
    const float inv_l = 1.f / lsum;
    const int q = q0 + w * 16 + quad * 4 + r;
#pragma unroll
    for (int nt = 0; nt < 4; ++nt) {
      const int d = nt * 16 + l16;
      const size_t f = (size_t)h2 * 262144 + (size_t)q * 128 + b2 * 64 + d;
      X[f] = f2bf_rn(o[nt][r] * inv_l);
    }
  }
}

// ---------------------------------------------------------------------------
// Kernel 5: out = X(bf16) @ Wc^T(bf16) + bc + query. 64x128 tile (384 blocks).
// ---------------------------------------------------------------------------
__global__ __launch_bounds__(256) void gemm2_kernel(
    const unsigned short* __restrict__ X, const unsigned short* __restrict__ Wcb,
    const float* __restrict__ bc, const float* __restrict__ query,
    float* __restrict__ out) {
  const int m0 = blockIdx.x * 64, n0 = blockIdx.y * 128;
  const int tid = threadIdx.x, lane = tid & 63, wid = tid >> 6;
  const int wm = wid >> 1, wn = wid & 1;
  const int l16 = lane & 15, quad = lane >> 4;

  __shared__ __align__(16) unsigned short As[64 * 32];
  __shared__ __align__(16) unsigned short Bs[128 * 32];

  v4f acc[2][4];
#pragma unroll
  for (int i = 0; i < 2; ++i)
#pragma unroll
    for (int j = 0; j < 4; ++j) { v4f z = {0.f, 0.f, 0.f, 0.f}; acc[i][j] = z; }

  for (int k0 = 0; k0 < 768; k0 += 32) {
    // A: 256 chunks, 1/lane
    load16_to_lds(X + (size_t)(m0 + (tid >> 2)) * 768 + k0 + (tid & 3) * 8,
                  &As[wid * 512]);
    // B: 512 chunks, 2/lane
#pragma unroll
    for (int iss = 0; iss < 2; ++iss) {
      const int c = wid * 128 + iss * 64 + lane;
      const int row = c >> 2, col8 = (c & 3) * 8;
      load16_to_lds(Wcb + (size_t)(n0 + row) * 768 + k0 + col8,
                    &Bs[(wid * 128 + iss * 64) * 8]);
    }
    __syncthreads();

    v8s af[2], bf[4];
#pragma unroll
    for (int i = 0; i < 2; ++i)
      af[i] = *(const v8s*)&As[(wm * 32 + i * 16 + l16) * 32 + quad * 8];
#pragma unroll
    for (int j = 0; j < 4; ++j)
      bf[j] = *(const v8s*)&Bs[(wn * 64 + j * 16 + l16) * 32 + quad * 8];
#pragma unroll
    for (int i = 0; i < 2; ++i)
#pragma unroll
      for (int j = 0; j < 4; ++j)
        acc[i][j] = __builtin_amdgcn_mfma_f32_16x16x32_bf16(af[i], bf[j],
                                                            acc[i][j], 0, 0, 0);
    __syncthreads();
  }

#pragma unroll
  for (int i = 0; i < 2; ++i) {
#pragma unroll
    for (int j = 0; j < 4; ++j) {
      const int mbase = m0 + wm * 32 + i * 16 + quad * 4;
      const int n = n0 + wn * 64 + j * 16 + l16;
      const float bv_ = bc[n];
#pragma unroll
      for (int r = 0; r < 4; ++r) {
        const int m = mbase + r;
        out[(size_t)m * 768 + n] =
            acc[i][j][r] + bv_ + query[(size_t)m * 768 + n];
      }
    }
  }
}

// ---------------------------------------------------------------------------
// Kernel 6: LayerNorm in place. One block per row.
// ---------------------------------------------------------------------------
__global__ __launch_bounds__(256) void ln_kernel(float* __restrict__ out,
                                                 const float* __restrict__ g,
                                                 const float* __restrict__ bta) {
  const int row = blockIdx.x;
  const int tid = threadIdx.x;
  float x[3];
  float s = 0.f, sq = 0.f;
#pragma unroll
  for (int k = 0; k < 3; ++k) {
    x[k] = out[(size_t)row * 768 + tid + k * 256];
    s += x[k];
    sq += x[k] * x[k];
  }
#pragma unroll
  for (int off = 1; off < 64; off <<= 1) {
    s += __shfl_xor(s, off, 64);
    sq += __shfl_xor(sq, off, 64);
  }
  __shared__ float ss[4], ssq[4];
  const int w = tid >> 6, lane = tid & 63;
  if (lane == 0) { ss[w] = s; ssq[w] = sq; }
  __syncthreads();
  s = ss[0] + ss[1] + ss[2] + ss[3];
  sq = ssq[0] + ssq[1] + ssq[2] + ssq[3];
  const float mu = s * (1.f / 768.f);
  const float var = sq * (1.f / 768.f) - mu * mu;
  const float rstd = rsqrtf(var + 1e-5f);
#pragma unroll
  for (int k = 0; k < 3; ++k) {
    const int cc = tid + k * 256;
    out[(size_t)row * 768 + cc] = g[cc] * (x[k] - mu) * rstd + bta[cc];
  }
}

// ---------------------------------------------------------------------------
extern "C" void kernel_launch(void* const* d_in, const int* in_sizes, int n_in,
                              void* d_out, int out_size, void* d_ws,
                              size_t ws_size, hipStream_t stream) {
  const float* key   = (const float*)d_in[0];
  const float* query = (const float*)d_in[1];
  const float* value = (const float*)d_in[2];
  const uint32_t* mask = (const uint32_t*)d_in[3];
  const float* Wk = (const float*)d_in[4];
  const float* bk = (const float*)d_in[5];
  const float* Wq = (const float*)d_in[6];
  const float* bq = (const float*)d_in[7];
  const float* Wv = (const float*)d_in[8];
  const float* bv = (const float*)d_in[9];
  const float* Wc = (const float*)d_in[10];
  const float* bc = (const float*)d_in[11];
  const float* lng = (const float*)d_in[12];
  const float* lnb = (const float*)d_in[13];

  char* ws = (char*)d_ws;
  uint32_t*       mbits = (uint32_t*)(ws);                   // 1 MB
  unsigned short* Wkb = (unsigned short*)(ws + 0x100000);    // 1.125 MB each
  unsigned short* Wqb = (unsigned short*)(ws + 0x220000);
  unsigned short* Wvb = (unsigned short*)(ws + 0x340000);
  unsigned short* Wcb = (unsigned short*)(ws + 0x460000);
  unsigned short* Qb  = (unsigned short*)(ws + 0x600000);    // 6 MB each
  unsigned short* Kb  = (unsigned short*)(ws + 0xC00000);
  unsigned short* Vt  = (unsigned short*)(ws + 0x1200000);
  unsigned short* X   = (unsigned short*)(ws + 0x1800000);   // end 30 MB
  float* out = (float*)d_out;

  pack_mask_kernel<<<dim3(1024), dim3(256), 0, stream>>>(mask, mbits);
  conv_w_kernel<<<dim3(576, 4), dim3(256), 0, stream>>>(Wk, Wq, Wv, Wc,
                                                        Wkb, Wqb, Wvb, Wcb);
  gemm_qkv_kernel<<<dim3(32, 6, 3), dim3(256), 0, stream>>>(
      query, key, value, Wqb, Wkb, Wvb, bq, bk, bv, Qb, Kb, Vt);
  attn_kernel<<<dim3(32, 12, 2), dim3(256), 0, stream>>>(Qb, Kb, Vt, mbits, X);
  gemm2_kernel<<<dim3(64, 6), dim3(256), 0, stream>>>(X, Wcb, bc, query, out);
  ln_kernel<<<dim3(4096), dim3(256), 0, stream>>>(out, lng, lnb);
}

// Round 3
// 243.878 us; speedup vs baseline: 1.3376x; 1.0232x over previous
//
#include <hip/hip_runtime.h>
#include <stdint.h>

// B=2, S=2048, D=768, H=12, hd=64
typedef float v4f __attribute__((ext_vector_type(4)));
typedef short v8s __attribute__((ext_vector_type(8)));

#define AS1 __attribute__((address_space(1)))
#define AS3 __attribute__((address_space(3)))

__device__ __forceinline__ void load16_to_lds(const void* g, void* l) {
  __builtin_amdgcn_global_load_lds((AS1 void*)g, (AS3 void*)l, 16, 0, 0);
}
__device__ __forceinline__ void load4_to_lds(const void* g, void* l) {
  __builtin_amdgcn_global_load_lds((AS1 void*)g, (AS3 void*)l, 4, 0, 0);
}

__device__ __forceinline__ float fexp2(float x) {
#if __has_builtin(__builtin_amdgcn_exp2f)
  return __builtin_amdgcn_exp2f(x);
#else
  return exp2f(x);
#endif
}

// round-half-up fp32 -> bf16
__device__ __forceinline__ unsigned short f2bf_rn(float f) {
  union { float f; uint32_t u; } v; v.f = f;
  return (unsigned short)((v.u + 0x8000u) >> 16);
}
// pack two fp32 -> bf16x2 dword via v_perm (x in low half)
__device__ __forceinline__ uint32_t pack_bf2(float x, float y) {
  union { float f; uint32_t u; } a, b; a.f = x; b.f = y;
  return __builtin_amdgcn_perm(b.u + 0x8000u, a.u + 0x8000u, 0x07060302u);
}

#define QSCALE 0.052058786f  // log2(e)/sqrt(768), folded into Wq & bq

// ---------------------------------------------------------------------------
// Kernel 1: pack mask into 1 bit/entry. int32 path: coalesced + __ballot.
// ---------------------------------------------------------------------------
__global__ __launch_bounds__(256) void pack_mask_kernel(
    const uint32_t* __restrict__ mask, uint32_t* __restrict__ bits) {
  __shared__ int s_i32;
  const int tid = threadIdx.x;
  if (tid == 0) s_i32 = 1;
  __syncthreads();
  if (mask[tid] > 1u) s_i32 = 0;   // byte-mode detector (P(fail) = 8^-256)
  __syncthreads();
  if (s_i32) {
    const int lane = tid & 63;
    const int gw = (blockIdx.x * 256 + tid) >> 6;  // 0..4095
#pragma unroll 4
    for (int it = 0; it < 32; ++it) {
      const size_t base = (size_t)gw * 2048 + it * 64;
      unsigned long long bal = __ballot(mask[base + lane] != 0u);
      if (lane == 0) *(unsigned long long*)&bits[base >> 5] = bal;
    }
  } else {
    const int wi = blockIdx.x * 256 + tid;
    const uint32_t* p = mask + (size_t)wi * 8;
    uint32_t w = 0;
#pragma unroll
    for (int j8 = 0; j8 < 8; ++j8) {
      uint32_t u = p[j8];
#pragma unroll
      for (int k = 0; k < 4; ++k)
        w |= (((u >> (8 * k)) & 0xFFu) ? 1u : 0u) << (j8 * 4 + k);
    }
    bits[wi] = w;
  }
}

// ---------------------------------------------------------------------------
// Kernel 2: convert weights (y=0..3) and inputs (y=4..6) fp32 -> bf16.
// Wq pre-scaled by QSCALE. grid (3072, 7) x 256; weights use x < 576 only.
// ---------------------------------------------------------------------------
__global__ __launch_bounds__(256) void conv_kernel(
    const float* __restrict__ wk, const float* __restrict__ wq,
    const float* __restrict__ wv, const float* __restrict__ wc,
    const float* __restrict__ kin, const float* __restrict__ qin,
    const float* __restrict__ vin,
    unsigned short* __restrict__ dk, unsigned short* __restrict__ dq,
    unsigned short* __restrict__ dv, unsigned short* __restrict__ dc,
    unsigned short* __restrict__ dki, unsigned short* __restrict__ dqi,
    unsigned short* __restrict__ dvi) {
  const int y = blockIdx.y;
  const float* s; unsigned short* d; float sc = 1.f; int n4;
  switch (y) {
    case 0: s = wk;  d = dk;  n4 = 147456; break;
    case 1: s = wq;  d = dq;  n4 = 147456; sc = QSCALE; break;
    case 2: s = wv;  d = dv;  n4 = 147456; break;
    case 3: s = wc;  d = dc;  n4 = 147456; break;
    case 4: s = kin; d = dki; n4 = 786432; break;
    case 5: s = qin; d = dqi; n4 = 786432; break;
    default: s = vin; d = dvi; n4 = 786432; break;
  }
  const int i = blockIdx.x * 256 + threadIdx.x;
  if (i >= n4) return;
  float4 f = ((const float4*)s)[i];
  uint2 o;
  o.x = pack_bf2(f.x * sc, f.y * sc);
  o.y = pack_bf2(f.z * sc, f.w * sc);
  ((uint2*)d)[i] = o;
}

// ---------------------------------------------------------------------------
// Kernel 3: QKV GEMM, all-bf16, pure global_load_lds staging, double-buffered
// LDS + single-barrier prefetch loop. 128x128 tile, BK=32, 4 waves 4x4 MFMA.
// z=0: Qin*Wq(scaled) -> Qb ; z=1: Kin*Wk -> Kb ; z=2: Vin*Wv -> Vt (transposed)
// ---------------------------------------------------------------------------
__global__ __launch_bounds__(256, 3) void gemm_qkv_kernel(
    const unsigned short* __restrict__ qin, const unsigned short* __restrict__ kin,
    const unsigned short* __restrict__ vin,
    const unsigned short* __restrict__ wqb, const unsigned short* __restrict__ wkb,
    const unsigned short* __restrict__ wvb,
    const float* __restrict__ bq, const float* __restrict__ bk,
    const float* __restrict__ bv,
    unsigned short* __restrict__ Qb, unsigned short* __restrict__ Kb,
    unsigned short* __restrict__ Vt) {
  const int which = blockIdx.z;
  const unsigned short* A; const unsigned short* Wb; const float* bias;
  float bscale = 1.f;
  if (which == 0)      { A = qin; Wb = wqb; bias = bq; bscale = QSCALE; }
  else if (which == 1) { A = kin; Wb = wkb; bias = bk; }
  else                 { A = vin; Wb = wvb; bias = bv; }

  const int m0 = blockIdx.x * 128, n0 = blockIdx.y * 128;
  const int tid = threadIdx.x, lane = tid & 63, wid = tid >> 6;
  const int wm = wid >> 1, wn = wid & 1;
  const int l16 = lane & 15, quad = lane >> 4;

  __shared__ __align__(16) unsigned short As[2][128 * 32];
  __shared__ __align__(16) unsigned short Bs[2][128 * 32];

  v4f acc[4][4];
#pragma unroll
  for (int i = 0; i < 4; ++i)
#pragma unroll
    for (int j = 0; j < 4; ++j) { v4f z = {0.f, 0.f, 0.f, 0.f}; acc[i][j] = z; }

  // per-lane staging geometry (chunk c: row=c>>2, col8=(c&3)*8)
  const int c0 = wid * 128 + lane, c1 = wid * 128 + 64 + lane;
  const unsigned short* a0 = A + (size_t)(m0 + (c0 >> 2)) * 768 + (c0 & 3) * 8;
  const unsigned short* a1 = A + (size_t)(m0 + (c1 >> 2)) * 768 + (c1 & 3) * 8;
  const unsigned short* b0 = Wb + (size_t)(n0 + (c0 >> 2)) * 768 + (c0 & 3) * 8;
  const unsigned short* b1 = Wb + (size_t)(n0 + (c1 >> 2)) * 768 + (c1 & 3) * 8;

#define QKV_STAGE(k0, buf)                                         \
  do {                                                             \
    load16_to_lds(a0 + (k0), &As[buf][(wid * 128) * 8]);           \
    load16_to_lds(a1 + (k0), &As[buf][(wid * 128 + 64) * 8]);      \
    load16_to_lds(b0 + (k0), &Bs[buf][(wid * 128) * 8]);           \
    load16_to_lds(b1 + (k0), &Bs[buf][(wid * 128 + 64) * 8]);      \
  } while (0)

  QKV_STAGE(0, 0);
#pragma unroll 2
  for (int ks = 0; ks < 24; ++ks) {
    const int bufc = ks & 1;
    __syncthreads();
    v8s af[4], bf[4];
#pragma unroll
    for (int i = 0; i < 4; ++i)
      af[i] = *(const v8s*)&As[bufc][(wm * 64 + i * 16 + l16) * 32 + quad * 8];
#pragma unroll
    for (int j = 0; j < 4; ++j)
      bf[j] = *(const v8s*)&Bs[bufc][(wn * 64 + j * 16 + l16) * 32 + quad * 8];
    if (ks < 23) QKV_STAGE((ks + 1) * 32, bufc ^ 1);
#pragma unroll
    for (int i = 0; i < 4; ++i)
#pragma unroll
      for (int j = 0; j < 4; ++j)
        acc[i][j] = __builtin_amdgcn_mfma_f32_16x16x32_bf16(af[i], bf[j],
                                                            acc[i][j], 0, 0, 0);
  }
#undef QKV_STAGE

#pragma unroll
  for (int i = 0; i < 4; ++i) {
#pragma unroll
    for (int j = 0; j < 4; ++j) {
      const int mbase = m0 + wm * 64 + i * 16 + quad * 4;
      const int n = n0 + wn * 64 + j * 16 + l16;
      const float bv_ = bias[n] * bscale;
      if (which == 2) {
        const int bb = mbase >> 11, ss = mbase & 2047;
        uint2 pk;
        pk.x = pack_bf2(acc[i][j][0] + bv_, acc[i][j][1] + bv_);
        pk.y = pack_bf2(acc[i][j][2] + bv_, acc[i][j][3] + bv_);
        *(uint2*)&Vt[((size_t)bb * 768 + n) * 2048 + ss] = pk;
      } else {
        unsigned short* dst = (which == 0) ? Qb : Kb;
#pragma unroll
        for (int r = 0; r < 4; ++r)
          dst[(size_t)(mbase + r) * 768 + n] = f2bf_rn(acc[i][j][r] + bv_);
      }
    }
  }
}

// ---------------------------------------------------------------------------
// Kernel 4: attention. No-max exp2 softmax (scale folded into Wq), denominator
// via ones-column MFMA, XOR-swizzled LDS, double-buffered K/V/mask with
// single-barrier prefetch loop. grid (32,12,2) x 256.
// ---------------------------------------------------------------------------
__global__ __launch_bounds__(256, 3) void attn_kernel(
    const unsigned short* __restrict__ Qb, const unsigned short* __restrict__ Kb,
    const unsigned short* __restrict__ Vt, const uint32_t* __restrict__ mbits,
    unsigned short* __restrict__ X) {
  const int q0 = blockIdx.x * 64;
  const int h = blockIdx.y, b = blockIdx.z;
  const int tid = threadIdx.x, w = tid >> 6, lane = tid & 63;
  const int l16 = lane & 15, quad = lane >> 4, l7 = l16 & 7;

  // rows of Kl/Vl/Pl are 128 B; 16B-chunk c of row r stored at c ^ (r&7).
  __shared__ __align__(16) unsigned short Kl[2][64 * 64];
  __shared__ __align__(16) unsigned short Vl[2][64 * 64];
  __shared__ __align__(16) unsigned short Pl[4][16 * 64];
  __shared__ uint32_t Ml[2][128];

  v8s aq[2];
  {
    const unsigned short* qp =
        Qb + (size_t)(b * 2048 + q0 + w * 16 + l16) * 768 + h * 64 + quad * 8;
    aq[0] = *(const v8s*)qp;
    aq[1] = *(const v8s*)(qp + 32);
  }

  v4f o[4], ol;
#pragma unroll
  for (int nt = 0; nt < 4; ++nt) { v4f z = {0.f, 0.f, 0.f, 0.f}; o[nt] = z; }
  { v4f z = {0.f, 0.f, 0.f, 0.f}; ol = z; }

  // ones-column B fragment: lane l16==0 holds B[0][k]=1.0bf16
  v8s bones;
  {
    const short v1 = (l16 == 0) ? (short)0x3F80 : (short)0;
#pragma unroll
    for (int j = 0; j < 8; ++j) bones[j] = v1;
  }

  const int rsub = lane >> 3;
  const int csub = ((lane & 7) ^ rsub) * 8;  // swizzled source chunk
  const unsigned short* kg0 = Kb + (size_t)(b * 2048 + w * 16) * 768 + h * 64;
  const unsigned short* vg0 = Vt + (size_t)(b * 768 + h * 64 + w * 16) * 2048;
  const uint32_t* mg0 =
      mbits + (size_t)(b * 2048 + q0 + w * 32 + (lane >> 1)) * 64 + (lane & 1);

#define ATTN_STAGE(kk0, buf)                                                  \
  do {                                                                        \
    const unsigned short* kg = kg0 + (size_t)(kk0) * 768;                     \
    const unsigned short* vg = vg0 + (kk0);                                   \
    load16_to_lds(kg + (size_t)rsub * 768 + csub, &Kl[buf][(w * 16) * 64]);   \
    load16_to_lds(kg + (size_t)(8 + rsub) * 768 + csub,                       \
                  &Kl[buf][(w * 16 + 8) * 64]);                               \
    load16_to_lds(vg + (size_t)rsub * 2048 + csub, &Vl[buf][(w * 16) * 64]);  \
    load16_to_lds(vg + (size_t)(8 + rsub) * 2048 + csub,                      \
                  &Vl[buf][(w * 16 + 8) * 64]);                               \
    if (w < 2) load4_to_lds(mg0 + ((kk0) >> 5), &Ml[buf][w * 64]);            \
  } while (0)

  ATTN_STAGE(0, 0);
#pragma unroll 2
  for (int it = 0; it < 32; ++it) {
    const int bufc = it & 1;
    __syncthreads();

    // K fragments first, then issue next tile's prefetch
    v8s bk[2][4];
#pragma unroll
    for (int kt = 0; kt < 2; ++kt)
#pragma unroll
      for (int nt = 0; nt < 4; ++nt)
        bk[kt][nt] = *(const v8s*)&Kl[bufc][(nt * 16 + l16) * 64 +
                                           (((kt * 4 + quad) ^ l7) << 3)];
    if (it < 31) ATTN_STAGE((it + 1) * 64, bufc ^ 1);

    // S = Q K^T (16 x 64 per wave), scores already x log2e/sqrt(768)
    v4f sacc[4];
#pragma unroll
    for (int nt = 0; nt < 4; ++nt) { v4f z = {0.f, 0.f, 0.f, 0.f}; sacc[nt] = z; }
#pragma unroll
    for (int kt = 0; kt < 2; ++kt)
#pragma unroll
      for (int nt = 0; nt < 4; ++nt)
        sacc[nt] = __builtin_amdgcn_mfma_f32_16x16x32_bf16(aq[kt], bk[kt][nt],
                                                           sacc[nt], 0, 0, 0);

    // P = mask ? 0 : exp2(S); write swizzled
    const int rowb = w * 16 + quad * 4;
    const int hi = l16 >> 3;
#pragma unroll
    for (int r = 0; r < 4; ++r) {
      const uint2 mw = *(const uint2*)&Ml[bufc][(rowb + r - w * 16 + w * 16) * 2];
      const uint32_t u0 = mw.x >> l16, u1 = mw.y >> l16;
      const float p0 = (u0 & 1u) ? 0.f : fexp2(sacc[0][r]);
      const float p1 = ((u0 >> 16) & 1u) ? 0.f : fexp2(sacc[1][r]);
      const float p2 = (u1 & 1u) ? 0.f : fexp2(sacc[2][r]);
      const float p3 = ((u1 >> 16) & 1u) ? 0.f : fexp2(sacc[3][r]);
      const int prow = quad * 4 + r, ps = prow & 7;
      const int base = prow * 64 + l7;
      Pl[w][base + (((0 + hi) ^ ps) << 3)] = f2bf_rn(p0);
      Pl[w][base + (((2 + hi) ^ ps) << 3)] = f2bf_rn(p1);
      Pl[w][base + (((4 + hi) ^ ps) << 3)] = f2bf_rn(p2);
      Pl[w][base + (((6 + hi) ^ ps) << 3)] = f2bf_rn(p3);
    }

    // O += P V ; row-sum l += P @ ones
#pragma unroll
    for (int kt = 0; kt < 2; ++kt) {
      const v8s ap = *(const v8s*)&Pl[w][l16 * 64 + (((kt * 4 + quad) ^ l7) << 3)];
#pragma unroll
      for (int nt = 0; nt < 4; ++nt) {
        const v8s bv = *(const v8s*)&Vl[bufc][(nt * 16 + l16) * 64 +
                                             (((kt * 4 + quad) ^ l7) << 3)];
        o[nt] = __builtin_amdgcn_mfma_f32_16x16x32_bf16(ap, bv, o[nt], 0, 0, 0);
      }
      ol = __builtin_amdgcn_mfma_f32_16x16x32_bf16(ap, bones, ol, 0, 0, 0);
    }
  }
#undef ATTN_STAGE

  // epilogue: faithful reshape scramble. 2h+b = 12*b2 + h2
  const int hb2 = 2 * h + b;
  const int b2 = (hb2 >= 12) ? 1 : 0;
  const int h2 = hb2 - 12 * b2;
#pragma unroll
  for (int r = 0; r < 4; ++r) {
    const float lsum = __shfl(ol[r], quad * 16, 64);  // col 0 holds the row sum
    const float inv_l = 1.f / lsum;
    const int q = q0 + w * 16 + quad * 4 + r;
#pragma unroll
    for (int nt = 0; nt < 4; ++nt) {
      const int d = nt * 16 + l16;
      const size_t f = (size_t)h2 * 262144 + (size_t)q * 128 + b2 * 64 + d;
      X[f] = f2bf_rn(o[nt][r] * inv_l);
    }
  }
}

// ---------------------------------------------------------------------------
// Kernel 5: out = X(bf16) @ Wc^T(bf16) + bc + query. 64x128 tile, dbuf
// prefetch loop. grid (64, 6).
// ---------------------------------------------------------------------------
__global__ __launch_bounds__(256, 3) void gemm2_kernel(
    const unsigned short* __restrict__ X, const unsigned short* __restrict__ Wcb,
    const float* __restrict__ bc, const float* __restrict__ query,
    float* __restrict__ out) {
  const int m0 = blockIdx.x * 64, n0 = blockIdx.y * 128;
  const int tid = threadIdx.x, lane = tid & 63, wid = tid >> 6;
  const int wm = wid >> 1, wn = wid & 1;
  const int l16 = lane & 15, quad = lane >> 4;

  __shared__ __align__(16) unsigned short As[2][64 * 32];
  __shared__ __align__(16) unsigned short Bs[2][128 * 32];

  v4f acc[2][4];
#pragma unroll
  for (int i = 0; i < 2; ++i)
#pragma unroll
    for (int j = 0; j < 4; ++j) { v4f z = {0.f, 0.f, 0.f, 0.f}; acc[i][j] = z; }

  const int ca = tid;  // A chunk
  const unsigned short* a0 = X + (size_t)(m0 + (ca >> 2)) * 768 + (ca & 3) * 8;
  const int c0 = wid * 128 + lane, c1 = wid * 128 + 64 + lane;
  const unsigned short* b0 = Wcb + (size_t)(n0 + (c0 >> 2)) * 768 + (c0 & 3) * 8;
  const unsigned short* b1 = Wcb + (size_t)(n0 + (c1 >> 2)) * 768 + (c1 & 3) * 8;

#define G2_STAGE(k0, buf)                                        \
  do {                                                           \
    load16_to_lds(a0 + (k0), &As[buf][(wid * 64) * 8]);          \
    load16_to_lds(b0 + (k0), &Bs[buf][(wid * 128) * 8]);         \
    load16_to_lds(b1 + (k0), &Bs[buf][(wid * 128 + 64) * 8]);    \
  } while (0)

  G2_STAGE(0, 0);
#pragma unroll 2
  for (int ks = 0; ks < 24; ++ks) {
    const int bufc = ks & 1;
    __syncthreads();
    v8s af[2], bf[4];
#pragma unroll
    for (int i = 0; i < 2; ++i)
      af[i] = *(const v8s*)&As[bufc][(wm * 32 + i * 16 + l16) * 32 + quad * 8];
#pragma unroll
    for (int j = 0; j < 4; ++j)
      bf[j] = *(const v8s*)&Bs[bufc][(wn * 64 + j * 16 + l16) * 32 + quad * 8];
    if (ks < 23) G2_STAGE((ks + 1) * 32, bufc ^ 1);
#pragma unroll
    for (int i = 0; i < 2; ++i)
#pragma unroll
      for (int j = 0; j < 4; ++j)
        acc[i][j] = __builtin_amdgcn_mfma_f32_16x16x32_bf16(af[i], bf[j],
                                                            acc[i][j], 0, 0, 0);
  }
#undef G2_STAGE

#pragma unroll
  for (int i = 0; i < 2; ++i) {
#pragma unroll
    for (int j = 0; j < 4; ++j) {
      const int mbase = m0 + wm * 32 + i * 16 + quad * 4;
      const int n = n0 + wn * 64 + j * 16 + l16;
      const float bv_ = bc[n];
#pragma unroll
      for (int r = 0; r < 4; ++r) {
        const int m = mbase + r;
        out[(size_t)m * 768 + n] =
            acc[i][j][r] + bv_ + query[(size_t)m * 768 + n];
      }
    }
  }
}

// ---------------------------------------------------------------------------
// Kernel 6: LayerNorm in place. One block per row.
// ---------------------------------------------------------------------------
__global__ __launch_bounds__(256) void ln_kernel(float* __restrict__ out,
                                                 const float* __restrict__ g,
                                                 const float* __restrict__ bta) {
  const int row = blockIdx.x;
  const int tid = threadIdx.x;
  float x[3];
  float s = 0.f, sq = 0.f;
#pragma unroll
  for (int k = 0; k < 3; ++k) {
    x[k] = out[(size_t)row * 768 + tid + k * 256];
    s += x[k];
    sq += x[k] * x[k];
  }
#pragma unroll
  for (int off = 1; off < 64; off <<= 1) {
    s += __shfl_xor(s, off, 64);
    sq += __shfl_xor(sq, off, 64);
  }
  __shared__ float ss[4], ssq[4];
  const int w = tid >> 6, lane = tid & 63;
  if (lane == 0) { ss[w] = s; ssq[w] = sq; }
  __syncthreads();
  s = ss[0] + ss[1] + ss[2] + ss[3];
  sq = ssq[0] + ssq[1] + ssq[2] + ssq[3];
  const float mu = s * (1.f / 768.f);
  const float var = sq * (1.f / 768.f) - mu * mu;
  const float rstd = rsqrtf(var + 1e-5f);
#pragma unroll
  for (int k = 0; k < 3; ++k) {
    const int cc = tid + k * 256;
    out[(size_t)row * 768 + cc] = g[cc] * (x[k] - mu) * rstd + bta[cc];
  }
}

// ---------------------------------------------------------------------------
extern "C" void kernel_launch(void* const* d_in, const int* in_sizes, int n_in,
                              void* d_out, int out_size, void* d_ws,
                              size_t ws_size, hipStream_t stream) {
  const float* key   = (const float*)d_in[0];
  const float* query = (const float*)d_in[1];
  const float* value = (const float*)d_in[2];
  const uint32_t* mask = (const uint32_t*)d_in[3];
  const float* Wk = (const float*)d_in[4];
  const float* bk = (const float*)d_in[5];
  const float* Wq = (const float*)d_in[6];
  const float* bq = (const float*)d_in[7];
  const float* Wv = (const float*)d_in[8];
  const float* bv = (const float*)d_in[9];
  const float* Wc = (const float*)d_in[10];
  const float* bc = (const float*)d_in[11];
  const float* lng = (const float*)d_in[12];
  const float* lnb = (const float*)d_in[13];

  char* ws = (char*)d_ws;
  uint32_t*       mbits = (uint32_t*)(ws);                   // 1 MB
  unsigned short* Wkb = (unsigned short*)(ws + 0x100000);    // 1.125 MB each
  unsigned short* Wqb = (unsigned short*)(ws + 0x220000);
  unsigned short* Wvb = (unsigned short*)(ws + 0x340000);
  unsigned short* Wcb = (unsigned short*)(ws + 0x460000);
  unsigned short* Qb  = (unsigned short*)(ws + 0x600000);    // 6 MB each
  unsigned short* Kb  = (unsigned short*)(ws + 0xC00000);
  unsigned short* Vt  = (unsigned short*)(ws + 0x1200000);
  unsigned short* X   = (unsigned short*)(ws + 0x1800000);   // also Vin (dead
                                                             // before X write)
  // bf16 input staging: Kin/Qin live in d_out (12.58 MB = exactly 2 buffers),
  // which is not written until gemm2.
  unsigned short* Kin = (unsigned short*)d_out;
  unsigned short* Qin = (unsigned short*)d_out + 3145728;
  unsigned short* Vin = X;
  float* out = (float*)d_out;

  pack_mask_kernel<<<dim3(1024), dim3(256), 0, stream>>>(mask, mbits);
  conv_kernel<<<dim3(3072, 7), dim3(256), 0, stream>>>(
      Wk, Wq, Wv, Wc, key, query, value,
      Wkb, Wqb, Wvb, Wcb, Kin, Qin, Vin);
  gemm_qkv_kernel<<<dim3(32, 6, 3), dim3(256), 0, stream>>>(
      Qin, Kin, Vin, Wqb, Wkb, Wvb, bq, bk, bv, Qb, Kb, Vt);
  attn_kernel<<<dim3(32, 12, 2), dim3(256), 0, stream>>>(Qb, Kb, Vt, mbits, X);
  gemm2_kernel<<<dim3(64, 6), dim3(256), 0, stream>>>(X, Wcb, bc, query, out);
  ln_kernel<<<dim3(4096), dim3(256), 0, stream>>>(out, lng, lnb);
}